// Round 13
// baseline (123.343 us; speedup 1.0000x reference)
//
#include <hip/hip_runtime.h>
#include <hip/hip_bf16.h>
#include <math.h>

#define HSZ 1024
#define NHD 16
#define SEQ 2048
#define BSZ 2
#define MTOT (BSZ*SEQ)   // 4096

typedef __attribute__((ext_vector_type(4)))  float  f32x4;
typedef __attribute__((ext_vector_type(8)))  __bf16 bf16x8;

#define LOG2E 1.4426950408889634f

#if __has_builtin(__builtin_amdgcn_exp2f)
#define EXP2(x) __builtin_amdgcn_exp2f(x)
#else
#define EXP2(x) exp2f(x)
#endif

__device__ __forceinline__ unsigned short f2bf(float x) {
    union { float f; unsigned u; } v; v.f = x;
    unsigned r = v.u + 0x7FFFu + ((v.u >> 16) & 1u);
    return (unsigned short)(r >> 16);
}
__device__ __forceinline__ float bf2f(unsigned short u) {
    union { unsigned u; float f; } v; v.u = ((unsigned)u) << 16; return v.f;
}
__device__ __forceinline__ unsigned cvtpk(float lo, float hi) {
    unsigned r;
    asm("v_cvt_pk_bf16_f32 %0, %1, %2" : "=v"(r) : "v"(lo), "v"(hi));
    return r;
}

// ---------------------------------------------------------------------------
// fp32 -> bf16 bulk convert: hidden + Wq/Wk/Wv, plus mexp table
// mexpb[b][kv] = bf16(exp2(mask*log2e))  (4096 elems, last 2 blocks).
// ---------------------------------------------------------------------------
__global__ __launch_bounds__(256) void cvt_all(
    const float* __restrict__ h,  unsigned short* __restrict__ hd,
    const float* __restrict__ w0, unsigned short* __restrict__ w0d,
    const float* __restrict__ w1, unsigned short* __restrict__ w1d,
    const float* __restrict__ w2, unsigned short* __restrict__ w2d,
    const float* __restrict__ mask, unsigned short* __restrict__ mexpb)
{
    const int bid = blockIdx.x;
    if (bid >= 3584) {   // mexp path
        const int o = ((bid - 3584) * 256 + threadIdx.x) * 8;
        float4 a = *(const float4*)(mask + o);
        float4 b = *(const float4*)(mask + o + 4);
        uint4 v;
        v.x = f2bf(EXP2(a.x * LOG2E)) | ((unsigned)f2bf(EXP2(a.y * LOG2E)) << 16);
        v.y = f2bf(EXP2(a.z * LOG2E)) | ((unsigned)f2bf(EXP2(a.w * LOG2E)) << 16);
        v.z = f2bf(EXP2(b.x * LOG2E)) | ((unsigned)f2bf(EXP2(b.y * LOG2E)) << 16);
        v.w = f2bf(EXP2(b.z * LOG2E)) | ((unsigned)f2bf(EXP2(b.w * LOG2E)) << 16);
        *(uint4*)(mexpb + o) = v;
        return;
    }
    const float* s; unsigned short* d; int i;
    if (bid < 2048)      { s = h;  d = hd;  i = bid; }
    else if (bid < 2560) { s = w0; d = w0d; i = bid - 2048; }
    else if (bid < 3072) { s = w1; d = w1d; i = bid - 2560; }
    else                 { s = w2; d = w2d; i = bid - 3072; }
    const int o = (i * 256 + threadIdx.x) * 8;
    float4 a = *(const float4*)(s + o);
    float4 b = *(const float4*)(s + o + 4);
    uint4 v;
    v.x = f2bf(a.x) | ((unsigned)f2bf(a.y) << 16);
    v.y = f2bf(a.z) | ((unsigned)f2bf(a.w) << 16);
    v.z = f2bf(b.x) | ((unsigned)f2bf(b.y) << 16);
    v.w = f2bf(b.z) | ((unsigned)f2bf(b.w) << 16);
    *(uint4*)(d + o) = v;
}

// ---------------------------------------------------------------------------
// Fused QKV GEMM, bf16 MFMA — BK=32 (verified fast). q scaled 0.125*log2e.
// V-blocks pre-load mexp factors (bf16 table) before the K-loop.
// K -> per-(b,h) 32 tiles of 8KB; elem (kv,d) at (kv&63)*128 + ((d*2)^((kv&7)<<4))
// V -> per-(b,h) 32 tiles of 8KB (V^T, mexp-scaled); elem (d,kv) at
//      d*128 + (((kv&63)*2) ^ ((d&7)<<4))
// ---------------------------------------------------------------------------
__global__ __launch_bounds__(256) void qkv_gemm(
    const unsigned short* __restrict__ hb,
    const unsigned short* __restrict__ wq,
    const unsigned short* __restrict__ wk,
    const unsigned short* __restrict__ wv,
    const float* __restrict__ bq, const float* __restrict__ bk,
    const float* __restrict__ bv, const unsigned short* __restrict__ mexpb,
    unsigned short* __restrict__ qo, char* __restrict__ ko,
    char* __restrict__ vo)
{
    __shared__ __align__(16) unsigned short As[128 * 32];   // 8 KB
    __shared__ __align__(16) unsigned short Bs[128 * 32];   // 8 KB

    const int t = threadIdx.x;
    const int w = t >> 6, l = t & 63, g = l >> 4, c = l & 15;
    const int bn = blockIdx.x, bm = blockIdx.y;
    const int which = bn >> 3;
    const int n0 = (bn & 7) << 7;
    const int m0 = bm << 7;
    const unsigned short* W = (which == 0) ? wq : (which == 1) ? wk : wv;
    const float* bb = (which == 0) ? bq : (which == 1) ? bk : bv;
    const float scale = (which == 0) ? 0.125f * LOG2E : 1.0f;
    const int wr = w >> 1, wc = w & 1;

    // V-blocks: hoist the 16 per-thread mexp factors (latency hidden by K-loop)
    float mexpf[16];
    if (which == 2) {
        #pragma unroll
        for (int mi = 0; mi < 4; ++mi) {
            const int mrow = m0 + wr * 64 + mi * 16 + g * 4;
            const int bi = mrow >> 11, si = mrow & 2047;
            const unsigned short* mp = mexpb + bi * SEQ + si;
            uint2 mv = *(const uint2*)mp;                  // 4 bf16
            mexpf[mi * 4 + 0] = bf2f((unsigned short)(mv.x & 0xFFFF));
            mexpf[mi * 4 + 1] = bf2f((unsigned short)(mv.x >> 16));
            mexpf[mi * 4 + 2] = bf2f((unsigned short)(mv.y & 0xFFFF));
            mexpf[mi * 4 + 3] = bf2f((unsigned short)(mv.y >> 16));
        }
    }

    f32x4 acc[4][4];
    #pragma unroll
    for (int mi = 0; mi < 4; ++mi)
        #pragma unroll
        for (int ni = 0; ni < 4; ++ni) acc[mi][ni] = {0.f, 0.f, 0.f, 0.f};

    for (int k0 = 0; k0 < HSZ; k0 += 32) {
        #pragma unroll
        for (int i2 = 0; i2 < 2; ++i2) {
            const int chunk = 2 * w + i2;
            const int row = (chunk << 4) + (l >> 2);
            const int sg = (l & 3) ^ ((row >> 1) & 3);
            const char* ga = (const char*)hb +
                (((size_t)(m0 + row) << 10) + k0) * 2 + sg * 16;
            const char* gb = (const char*)W +
                (((size_t)(n0 + row) << 10) + k0) * 2 + sg * 16;
            __builtin_amdgcn_global_load_lds(
                (const __attribute__((address_space(1))) unsigned*)ga,
                (__attribute__((address_space(3))) unsigned*)((char*)As + chunk * 1024),
                16, 0, 0);
            __builtin_amdgcn_global_load_lds(
                (const __attribute__((address_space(1))) unsigned*)gb,
                (__attribute__((address_space(3))) unsigned*)((char*)Bs + chunk * 1024),
                16, 0, 0);
        }
        __syncthreads();

        bf16x8 af[4], bfr[4];
        #pragma unroll
        for (int mi = 0; mi < 4; ++mi) {
            const int row = wr * 64 + mi * 16 + c;
            const int gg = g ^ ((row >> 1) & 3);
            af[mi] = *(const bf16x8*)((const char*)As + row * 64 + gg * 16);
        }
        #pragma unroll
        for (int ni = 0; ni < 4; ++ni) {
            const int row = wc * 64 + ni * 16 + c;
            const int gg = g ^ ((row >> 1) & 3);
            bfr[ni] = *(const bf16x8*)((const char*)Bs + row * 64 + gg * 16);
        }
        #pragma unroll
        for (int mi = 0; mi < 4; ++mi)
            #pragma unroll
            for (int ni = 0; ni < 4; ++ni)
                acc[mi][ni] = __builtin_amdgcn_mfma_f32_16x16x32_bf16(
                    af[mi], bfr[ni], acc[mi][ni], 0, 0, 0);
        __syncthreads();
    }

    #pragma unroll
    for (int ni = 0; ni < 4; ++ni) {
        const int ncol = n0 + wc * 64 + ni * 16 + c;
        const int hh = ncol >> 6, d = ncol & 63;
        const float bsc = bb[ncol] * scale;
        #pragma unroll
        for (int mi = 0; mi < 4; ++mi) {
            #pragma unroll
            for (int j = 0; j < 4; ++j) {
                const int mrow = m0 + wr * 64 + mi * 16 + g * 4 + j;
                const int bi = mrow >> 11, si = mrow & 2047;
                float vf = acc[mi][ni][j] * scale + bsc;
                if (which == 2) vf *= mexpf[mi * 4 + j];   // register-only
                const unsigned short val = f2bf(vf);
                const size_t bhoff = (size_t)(bi * NHD + hh);
                if (which == 0) {
                    qo[((bhoff * SEQ + si) << 6) + d] = val;
                } else if (which == 1) {
                    char* p = ko + (bhoff << 18) + ((size_t)(si >> 6) << 13)
                            + ((si & 63) << 7) + (((d << 1)) ^ ((si & 7) << 4));
                    *(unsigned short*)p = val;
                } else {
                    char* p = vo + (bhoff << 18) + ((size_t)(si >> 6) << 13)
                            + (d << 7) + (((si & 63) << 1) ^ ((d & 7) << 4));
                    *(unsigned short*)p = val;
                }
            }
        }
    }
}

// ---------------------------------------------------------------------------
// Flash attention, kv-split: block = 64 q-rows, 4 waves. Waves {0,1} do
// kv 0..1023 (tiles 0..15), waves {2,3} kv 1024..2047 (tiles 16..31); wave w
// and w+2 hold identical-layout partials for the same 32 q-rows (max-free
// softmax => partials combine by simple addition in LDS at the end).
// Grid 32 x NHD x BSZ = 1024 blocks -> 4 blocks/CU, 16 waves/CU.
// K/V single-buffered per pair (Kt[pair]/Vt[pair], 16KB/pair).
// ---------------------------------------------------------------------------
__global__ __launch_bounds__(256) void attn_mfma(
    const unsigned short* __restrict__ qb, const char* __restrict__ kb,
    const char* __restrict__ vb, const unsigned short* __restrict__ mexpb,
    float* __restrict__ out)
{
    __shared__ __align__(16) char Kt[2][8192];         // per PAIR (not dbuf)
    __shared__ __align__(16) char Vt[2][8192];
    __shared__ __align__(16) unsigned Pl[4][16][32];   // total LDS = 40960 B

    const int t = threadIdx.x;
    const int w = t >> 6, l = t & 63, g = l >> 4, c = l & 15;
    const int pair = w >> 1, wq = w & 1;
    const int qt = blockIdx.x, h = blockIdx.y, b = blockIdx.z;
    const int bh = b * NHD + h;
    const int q0 = qt * 64 + wq * 32;

    const unsigned short* qp = qb + ((size_t)bh * SEQ + q0) * 64;
    const char* kbase = kb + ((size_t)bh << 18);
    const char* vbase = vb + ((size_t)bh << 18);
    const unsigned short* mep = mexpb + b * SEQ;

    // Q B-fragments for both 16-row halves (col = q = qh*16+c, k = 8g+e)
    bf16x8 qf[2][2];
    #pragma unroll
    for (int qh = 0; qh < 2; ++qh)
        #pragma unroll
        for (int p = 0; p < 2; ++p)
            qf[qh][p] = *(const bf16x8*)(qp + (qh * 16 + c) * 64 + p * 32 + g * 8);

    f32x4 o0[4], o1[4];
    #pragma unroll
    for (int tt = 0; tt < 4; ++tt) { o0[tt] = {0.f,0.f,0.f,0.f}; o1[tt] = {0.f,0.f,0.f,0.f}; }
    f32x4 ls0 = {0.f,0.f,0.f,0.f}, ls1 = {0.f,0.f,0.f,0.f};

    // stage own pair's tile; wave covers half wq (4KB of K + 4KB of V)
    auto STAGE = [&](int tile) {
        const char* kg = kbase + tile * 8192 + wq * 4096 + l * 16;
        const char* vg = vbase + tile * 8192 + wq * 4096 + l * 16;
        #pragma unroll
        for (int i = 0; i < 4; ++i) {
            __builtin_amdgcn_global_load_lds(
                (const __attribute__((address_space(1))) unsigned*)(kg + i * 1024),
                (__attribute__((address_space(3))) unsigned*)(&Kt[pair][wq * 4096 + i * 1024]),
                16, 0, 0);
            __builtin_amdgcn_global_load_lds(
                (const __attribute__((address_space(1))) unsigned*)(vg + i * 1024),
                (__attribute__((address_space(3))) unsigned*)(&Vt[pair][wq * 4096 + i * 1024]),
                16, 0, 0);
        }
    };

    STAGE(pair * 16);
    __syncthreads();   // drain -> tile resident

    for (int i = 0; i < 16; ++i) {
        const int kv0 = (pair * 16 + i) * 64;

        // mexp A-frags (broadcast rows; shared by both halves)
        bf16x8 mf[2];
        #pragma unroll
        for (int blk = 0; blk < 2; ++blk)
            mf[blk] = *(const bf16x8*)(mep + kv0 + blk * 32 + g * 8);

        // ---- QK^T both halves; K frag loaded once per t2, used twice ----
        f32x4 s0[4], s1[4];
        #pragma unroll
        for (int t2 = 0; t2 < 4; ++t2) { s0[t2] = {0.f,0.f,0.f,0.f}; s1[t2] = {0.f,0.f,0.f,0.f}; }
        __builtin_amdgcn_s_setprio(1);
        #pragma unroll
        for (int t2 = 0; t2 < 4; ++t2) {
            const bf16x8 k0 = *(const bf16x8*)(&Kt[pair][(t2 * 16 + c) * 128
                                 + ((g * 16) ^ ((c & 7) << 4))]);
            const bf16x8 k1 = *(const bf16x8*)(&Kt[pair][(t2 * 16 + c) * 128
                                 + ((64 + g * 16) ^ ((c & 7) << 4))]);
            s0[t2] = __builtin_amdgcn_mfma_f32_16x16x32_bf16(k0, qf[0][0], s0[t2], 0, 0, 0);
            s0[t2] = __builtin_amdgcn_mfma_f32_16x16x32_bf16(k1, qf[0][1], s0[t2], 0, 0, 0);
            s1[t2] = __builtin_amdgcn_mfma_f32_16x16x32_bf16(k0, qf[1][0], s1[t2], 0, 0, 0);
            s1[t2] = __builtin_amdgcn_mfma_f32_16x16x32_bf16(k1, qf[1][1], s1[t2], 0, 0, 0);
        }
        __builtin_amdgcn_s_setprio(0);

        // ---- V^T fragments loaded once, used by both halves ----
        bf16x8 vfr[4][2];
        #pragma unroll
        for (int tt = 0; tt < 4; ++tt)
            #pragma unroll
            for (int blk = 0; blk < 2; ++blk)
                vfr[tt][blk] = *(const bf16x8*)(&Vt[pair][(tt * 16 + c) * 128
                                     + ((blk * 64 + g * 16) ^ ((c & 7) << 4))]);

        // ---- half 0: exp, P roundtrip, lsum + PV ----
        #pragma unroll
        for (int t2 = 0; t2 < 4; ++t2) {
            s0[t2][0] = EXP2(s0[t2][0]); s0[t2][1] = EXP2(s0[t2][1]);
            s0[t2][2] = EXP2(s0[t2][2]); s0[t2][3] = EXP2(s0[t2][3]);
        }
        #pragma unroll
        for (int t2 = 0; t2 < 4; ++t2) {
            uint2 pr;
            pr.x = cvtpk(s0[t2][0], s0[t2][1]);
            pr.y = cvtpk(s0[t2][2], s0[t2][3]);
            *(uint2*)&Pl[w][c][(8 * t2 + 2 * g) ^ ((c & 7) << 2)] = pr;
        }
        {
            bf16x8 pfr[2];
            #pragma unroll
            for (int blk = 0; blk < 2; ++blk)
                pfr[blk] = *(const bf16x8*)&Pl[w][c][(16 * blk + 4 * g) ^ ((c & 7) << 2)];
            __builtin_amdgcn_s_setprio(1);
            #pragma unroll
            for (int blk = 0; blk < 2; ++blk)
                ls0 = __builtin_amdgcn_mfma_f32_16x16x32_bf16(mf[blk], pfr[blk], ls0, 0, 0, 0);
            #pragma unroll
            for (int tt = 0; tt < 4; ++tt)
                #pragma unroll
                for (int blk = 0; blk < 2; ++blk)
                    o0[tt] = __builtin_amdgcn_mfma_f32_16x16x32_bf16(vfr[tt][blk], pfr[blk], o0[tt], 0, 0, 0);
            __builtin_amdgcn_s_setprio(0);
        }

        // ---- half 1 ----
        #pragma unroll
        for (int t2 = 0; t2 < 4; ++t2) {
            s1[t2][0] = EXP2(s1[t2][0]); s1[t2][1] = EXP2(s1[t2][1]);
            s1[t2][2] = EXP2(s1[t2][2]); s1[t2][3] = EXP2(s1[t2][3]);
        }
        #pragma unroll
        for (int t2 = 0; t2 < 4; ++t2) {
            uint2 pr;
            pr.x = cvtpk(s1[t2][0], s1[t2][1]);
            pr.y = cvtpk(s1[t2][2], s1[t2][3]);
            *(uint2*)&Pl[w][c][(8 * t2 + 2 * g) ^ ((c & 7) << 2)] = pr;
        }
        {
            bf16x8 pfr[2];
            #pragma unroll
            for (int blk = 0; blk < 2; ++blk)
                pfr[blk] = *(const bf16x8*)&Pl[w][c][(16 * blk + 4 * g) ^ ((c & 7) << 2)];
            __builtin_amdgcn_s_setprio(1);
            #pragma unroll
            for (int blk = 0; blk < 2; ++blk)
                ls1 = __builtin_amdgcn_mfma_f32_16x16x32_bf16(mf[blk], pfr[blk], ls1, 0, 0, 0);
            #pragma unroll
            for (int tt = 0; tt < 4; ++tt)
                #pragma unroll
                for (int blk = 0; blk < 2; ++blk)
                    o1[tt] = __builtin_amdgcn_mfma_f32_16x16x32_bf16(vfr[tt][blk], pfr[blk], o1[tt], 0, 0, 0);
            __builtin_amdgcn_s_setprio(0);
        }

        __syncthreads();                        // all done reading tile i
        if (i < 15) STAGE(pair * 16 + i + 1);   // overwrite now safe
        __syncthreads();                        // drain -> tile i+1 resident
    }

    // ---- combine kv-halves: waves 2,3 dump partials into dead K/V LDS ----
    if (w >= 2) {
        char* dst = (char*)Kt + (w - 2) * 8192;
        #pragma unroll
        for (int tt = 0; tt < 4; ++tt)
            #pragma unroll
            for (int j = 0; j < 4; ++j) {
                *(float*)(dst + (16 * tt + 4 * g + j) * 64 + c * 4) = o0[tt][j];
                *(float*)(dst + 4096 + (16 * tt + 4 * g + j) * 64 + c * 4) = o1[tt][j];
            }
        Pl[w][0][c] = __float_as_uint(ls0[0]);
        Pl[w][1][c] = __float_as_uint(ls1[0]);
    }
    __syncthreads();
    if (w < 2) {
        const char* src = (const char*)Kt + w * 8192;
        #pragma unroll
        for (int tt = 0; tt < 4; ++tt)
            #pragma unroll
            for (int j = 0; j < 4; ++j) {
                o0[tt][j] += *(const float*)(src + (16 * tt + 4 * g + j) * 64 + c * 4);
                o1[tt][j] += *(const float*)(src + 4096 + (16 * tt + 4 * g + j) * 64 + c * 4);
            }
        const float li0 = 1.f / (ls0[0] + __uint_as_float(Pl[w + 2][0][c]));
        const float li1 = 1.f / (ls1[0] + __uint_as_float(Pl[w + 2][1][c]));
        #pragma unroll
        for (int tt = 0; tt < 4; ++tt) {
            const size_t r0 = ((size_t)(b * SEQ + q0 + c) << 10) + h * 64 + 16 * tt + 4 * g;
            out[r0 + 0] = o0[tt][0] * li0;
            out[r0 + 1] = o0[tt][1] * li0;
            out[r0 + 2] = o0[tt][2] * li0;
            out[r0 + 3] = o0[tt][3] * li0;
            const size_t r1 = ((size_t)(b * SEQ + q0 + 16 + c) << 10) + h * 64 + 16 * tt + 4 * g;
            out[r1 + 0] = o1[tt][0] * li1;
            out[r1 + 1] = o1[tt][1] * li1;
            out[r1 + 2] = o1[tt][2] * li1;
            out[r1 + 3] = o1[tt][3] * li1;
        }
    }
}

extern "C" void kernel_launch(void* const* d_in, const int* in_sizes, int n_in,
                              void* d_out, int out_size, void* d_ws, size_t ws_size,
                              hipStream_t stream) {
    const float* hid  = (const float*)d_in[0];
    const float* mask = (const float*)d_in[1];
    const float* Wq   = (const float*)d_in[2];
    const float* bq   = (const float*)d_in[3];
    const float* Wk   = (const float*)d_in[4];
    const float* bk   = (const float*)d_in[5];
    const float* Wv   = (const float*)d_in[6];
    const float* bv   = (const float*)d_in[7];
    float* out = (float*)d_out;

    char* ws = (char*)d_ws;
    unsigned short* qbf = (unsigned short*)(ws);                    // 8 MB
    char*           kbf = ws + 8388608;                             // 8 MB (tiled+swz)
    char*           vbf = ws + 16777216;                            // 8 MB (V^T tiled+swz, mexp-scaled)
    unsigned short* hbf = (unsigned short*)(ws + 25165824);         // 8 MB
    unsigned short* wqb = (unsigned short*)(ws + 33554432);         // 2 MB
    unsigned short* wkb = (unsigned short*)(ws + 35651584);         // 2 MB
    unsigned short* wvb = (unsigned short*)(ws + 37748736);         // 2 MB
    unsigned short* mxb = (unsigned short*)(ws + 39845888);         // 8 KB mexp table

    cvt_all<<<3586, 256, 0, stream>>>(hid, hbf, Wq, wqb, Wk, wkb, Wv, wvb,
                                      mask, mxb);
    qkv_gemm<<<dim3(24, 32), 256, 0, stream>>>(hbf, wqb, wkb, wvb,
                                               bq, bk, bv, mxb, qbf, kbf, vbf);
    attn_mfma<<<dim3(32, NHD, BSZ), 256, 0, stream>>>(qbf, kbf, vbf, mxb, out);
}

// Round 14
// 120.538 us; speedup vs baseline: 1.0233x; 1.0233x over previous
//
#include <hip/hip_runtime.h>
#include <hip/hip_bf16.h>
#include <math.h>

#define HSZ 1024
#define NHD 16
#define SEQ 2048
#define BSZ 2
#define MTOT (BSZ*SEQ)   // 4096

typedef __attribute__((ext_vector_type(4)))  float  f32x4;
typedef __attribute__((ext_vector_type(8)))  __bf16 bf16x8;

#define LOG2E 1.4426950408889634f

#if __has_builtin(__builtin_amdgcn_exp2f)
#define EXP2(x) __builtin_amdgcn_exp2f(x)
#else
#define EXP2(x) exp2f(x)
#endif

__device__ __forceinline__ unsigned short f2bf(float x) {
    union { float f; unsigned u; } v; v.f = x;
    unsigned r = v.u + 0x7FFFu + ((v.u >> 16) & 1u);
    return (unsigned short)(r >> 16);
}
__device__ __forceinline__ float bf2f(unsigned short u) {
    union { unsigned u; float f; } v; v.u = ((unsigned)u) << 16; return v.f;
}
__device__ __forceinline__ unsigned cvtpk(float lo, float hi) {
    unsigned r;
    asm("v_cvt_pk_bf16_f32 %0, %1, %2" : "=v"(r) : "v"(lo), "v"(hi));
    return r;
}

// ---------------------------------------------------------------------------
// fp32 -> bf16 bulk convert: hidden + Wq/Wk/Wv, plus mexp table
// mexpb[b][kv] = bf16(exp2(mask*log2e))  (4096 elems, last 2 blocks).
// ---------------------------------------------------------------------------
__global__ __launch_bounds__(256) void cvt_all(
    const float* __restrict__ h,  unsigned short* __restrict__ hd,
    const float* __restrict__ w0, unsigned short* __restrict__ w0d,
    const float* __restrict__ w1, unsigned short* __restrict__ w1d,
    const float* __restrict__ w2, unsigned short* __restrict__ w2d,
    const float* __restrict__ mask, unsigned short* __restrict__ mexpb)
{
    const int bid = blockIdx.x;
    if (bid >= 3584) {   // mexp path
        const int o = ((bid - 3584) * 256 + threadIdx.x) * 8;
        float4 a = *(const float4*)(mask + o);
        float4 b = *(const float4*)(mask + o + 4);
        uint4 v;
        v.x = f2bf(EXP2(a.x * LOG2E)) | ((unsigned)f2bf(EXP2(a.y * LOG2E)) << 16);
        v.y = f2bf(EXP2(a.z * LOG2E)) | ((unsigned)f2bf(EXP2(a.w * LOG2E)) << 16);
        v.z = f2bf(EXP2(b.x * LOG2E)) | ((unsigned)f2bf(EXP2(b.y * LOG2E)) << 16);
        v.w = f2bf(EXP2(b.z * LOG2E)) | ((unsigned)f2bf(EXP2(b.w * LOG2E)) << 16);
        *(uint4*)(mexpb + o) = v;
        return;
    }
    const float* s; unsigned short* d; int i;
    if (bid < 2048)      { s = h;  d = hd;  i = bid; }
    else if (bid < 2560) { s = w0; d = w0d; i = bid - 2048; }
    else if (bid < 3072) { s = w1; d = w1d; i = bid - 2560; }
    else                 { s = w2; d = w2d; i = bid - 3072; }
    const int o = (i * 256 + threadIdx.x) * 8;
    float4 a = *(const float4*)(s + o);
    float4 b = *(const float4*)(s + o + 4);
    uint4 v;
    v.x = f2bf(a.x) | ((unsigned)f2bf(a.y) << 16);
    v.y = f2bf(a.z) | ((unsigned)f2bf(a.w) << 16);
    v.z = f2bf(b.x) | ((unsigned)f2bf(b.y) << 16);
    v.w = f2bf(b.z) | ((unsigned)f2bf(b.w) << 16);
    *(uint4*)(d + o) = v;
}

// ---------------------------------------------------------------------------
// Fused QKV GEMM, bf16 MFMA — BK=32 (verified fast). q scaled 0.125*log2e.
// V-blocks pre-load mexp factors (bf16 table) before the K-loop.
// K -> per-(b,h) 32 tiles of 8KB; elem (kv,d) at (kv&63)*128 + ((d*2)^((kv&7)<<4))
// V -> per-(b,h) 32 tiles of 8KB (V^T, mexp-scaled); elem (d,kv) at
//      d*128 + (((kv&63)*2) ^ ((d&7)<<4))
// ---------------------------------------------------------------------------
__global__ __launch_bounds__(256) void qkv_gemm(
    const unsigned short* __restrict__ hb,
    const unsigned short* __restrict__ wq,
    const unsigned short* __restrict__ wk,
    const unsigned short* __restrict__ wv,
    const float* __restrict__ bq, const float* __restrict__ bk,
    const float* __restrict__ bv, const unsigned short* __restrict__ mexpb,
    unsigned short* __restrict__ qo, char* __restrict__ ko,
    char* __restrict__ vo)
{
    __shared__ __align__(16) unsigned short As[128 * 32];   // 8 KB
    __shared__ __align__(16) unsigned short Bs[128 * 32];   // 8 KB

    const int t = threadIdx.x;
    const int w = t >> 6, l = t & 63, g = l >> 4, c = l & 15;
    const int bn = blockIdx.x, bm = blockIdx.y;
    const int which = bn >> 3;
    const int n0 = (bn & 7) << 7;
    const int m0 = bm << 7;
    const unsigned short* W = (which == 0) ? wq : (which == 1) ? wk : wv;
    const float* bb = (which == 0) ? bq : (which == 1) ? bk : bv;
    const float scale = (which == 0) ? 0.125f * LOG2E : 1.0f;
    const int wr = w >> 1, wc = w & 1;

    // V-blocks: hoist the 16 per-thread mexp factors (latency hidden by K-loop)
    float mexpf[16];
    if (which == 2) {
        #pragma unroll
        for (int mi = 0; mi < 4; ++mi) {
            const int mrow = m0 + wr * 64 + mi * 16 + g * 4;
            const int bi = mrow >> 11, si = mrow & 2047;
            const unsigned short* mp = mexpb + bi * SEQ + si;
            uint2 mv = *(const uint2*)mp;                  // 4 bf16
            mexpf[mi * 4 + 0] = bf2f((unsigned short)(mv.x & 0xFFFF));
            mexpf[mi * 4 + 1] = bf2f((unsigned short)(mv.x >> 16));
            mexpf[mi * 4 + 2] = bf2f((unsigned short)(mv.y & 0xFFFF));
            mexpf[mi * 4 + 3] = bf2f((unsigned short)(mv.y >> 16));
        }
    }

    f32x4 acc[4][4];
    #pragma unroll
    for (int mi = 0; mi < 4; ++mi)
        #pragma unroll
        for (int ni = 0; ni < 4; ++ni) acc[mi][ni] = {0.f, 0.f, 0.f, 0.f};

    for (int k0 = 0; k0 < HSZ; k0 += 32) {
        #pragma unroll
        for (int i2 = 0; i2 < 2; ++i2) {
            const int chunk = 2 * w + i2;
            const int row = (chunk << 4) + (l >> 2);
            const int sg = (l & 3) ^ ((row >> 1) & 3);
            const char* ga = (const char*)hb +
                (((size_t)(m0 + row) << 10) + k0) * 2 + sg * 16;
            const char* gb = (const char*)W +
                (((size_t)(n0 + row) << 10) + k0) * 2 + sg * 16;
            __builtin_amdgcn_global_load_lds(
                (const __attribute__((address_space(1))) unsigned*)ga,
                (__attribute__((address_space(3))) unsigned*)((char*)As + chunk * 1024),
                16, 0, 0);
            __builtin_amdgcn_global_load_lds(
                (const __attribute__((address_space(1))) unsigned*)gb,
                (__attribute__((address_space(3))) unsigned*)((char*)Bs + chunk * 1024),
                16, 0, 0);
        }
        __syncthreads();

        bf16x8 af[4], bfr[4];
        #pragma unroll
        for (int mi = 0; mi < 4; ++mi) {
            const int row = wr * 64 + mi * 16 + c;
            const int gg = g ^ ((row >> 1) & 3);
            af[mi] = *(const bf16x8*)((const char*)As + row * 64 + gg * 16);
        }
        #pragma unroll
        for (int ni = 0; ni < 4; ++ni) {
            const int row = wc * 64 + ni * 16 + c;
            const int gg = g ^ ((row >> 1) & 3);
            bfr[ni] = *(const bf16x8*)((const char*)Bs + row * 64 + gg * 16);
        }
        #pragma unroll
        for (int mi = 0; mi < 4; ++mi)
            #pragma unroll
            for (int ni = 0; ni < 4; ++ni)
                acc[mi][ni] = __builtin_amdgcn_mfma_f32_16x16x32_bf16(
                    af[mi], bfr[ni], acc[mi][ni], 0, 0, 0);
        __syncthreads();
    }

    #pragma unroll
    for (int ni = 0; ni < 4; ++ni) {
        const int ncol = n0 + wc * 64 + ni * 16 + c;
        const int hh = ncol >> 6, d = ncol & 63;
        const float bsc = bb[ncol] * scale;
        #pragma unroll
        for (int mi = 0; mi < 4; ++mi) {
            #pragma unroll
            for (int j = 0; j < 4; ++j) {
                const int mrow = m0 + wr * 64 + mi * 16 + g * 4 + j;
                const int bi = mrow >> 11, si = mrow & 2047;
                float vf = acc[mi][ni][j] * scale + bsc;
                if (which == 2) vf *= mexpf[mi * 4 + j];   // register-only
                const unsigned short val = f2bf(vf);
                const size_t bhoff = (size_t)(bi * NHD + hh);
                if (which == 0) {
                    qo[((bhoff * SEQ + si) << 6) + d] = val;
                } else if (which == 1) {
                    char* p = ko + (bhoff << 18) + ((size_t)(si >> 6) << 13)
                            + ((si & 63) << 7) + (((d << 1)) ^ ((si & 7) << 4));
                    *(unsigned short*)p = val;
                } else {
                    char* p = vo + (bhoff << 18) + ((size_t)(si >> 6) << 13)
                            + (d << 7) + (((si & 63) << 1) ^ ((d & 7) << 4));
                    *(unsigned short*)p = val;
                }
            }
        }
    }
}

// ---------------------------------------------------------------------------
// Flash attention: round-12 per-wave structure re-partitioned into 2-WAVE
// blocks (64 q-rows each, 32/wave). LDS 36 KB -> 4 blocks/CU -> 4 independent
// barrier/drain streams per CU (vs 2), cheaper 2-wave barriers. Max-free
// softmax; mask pre-folded into V; denominator via MFMA; K/V double-buffered.
// Grid 32 x NHD x BSZ = 1024 blocks of 128 threads.
// ---------------------------------------------------------------------------
__global__ __launch_bounds__(128) void attn_mfma(
    const unsigned short* __restrict__ qb, const char* __restrict__ kb,
    const char* __restrict__ vb, const unsigned short* __restrict__ mexpb,
    float* __restrict__ out)
{
    __shared__ __align__(16) char Kt[2][8192];
    __shared__ __align__(16) char Vt[2][8192];
    __shared__ __align__(16) unsigned Pl[2][16][32];   // total LDS = 36864 B

    const int t = threadIdx.x;
    const int w = t >> 6, l = t & 63, g = l >> 4, c = l & 15;
    const int qt = blockIdx.x, h = blockIdx.y, b = blockIdx.z;
    const int bh = b * NHD + h;
    const int q0 = qt * 64 + w * 32;

    const unsigned short* qp = qb + ((size_t)bh * SEQ + q0) * 64;
    const char* kbase = kb + ((size_t)bh << 18);
    const char* vbase = vb + ((size_t)bh << 18);
    const unsigned short* mep = mexpb + b * SEQ;

    // Q B-fragments for both 16-row halves (col = q = qh*16+c, k = 8g+e)
    bf16x8 qf[2][2];
    #pragma unroll
    for (int qh = 0; qh < 2; ++qh)
        #pragma unroll
        for (int p = 0; p < 2; ++p)
            qf[qh][p] = *(const bf16x8*)(qp + (qh * 16 + c) * 64 + p * 32 + g * 8);

    f32x4 o0[4], o1[4];
    #pragma unroll
    for (int tt = 0; tt < 4; ++tt) { o0[tt] = {0.f,0.f,0.f,0.f}; o1[tt] = {0.f,0.f,0.f,0.f}; }
    f32x4 ls0 = {0.f,0.f,0.f,0.f}, ls1 = {0.f,0.f,0.f,0.f};

    // staging: wave w copies bytes [w*4096, w*4096+4096) of each 8KB tile
    auto STAGE = [&](int tile, int buf) {
        const char* kg = kbase + tile * 8192 + w * 4096 + l * 16;
        const char* vg = vbase + tile * 8192 + w * 4096 + l * 16;
        #pragma unroll
        for (int i = 0; i < 4; ++i) {
            __builtin_amdgcn_global_load_lds(
                (const __attribute__((address_space(1))) unsigned*)(kg + i * 1024),
                (__attribute__((address_space(3))) unsigned*)(&Kt[buf][w * 4096 + i * 1024]),
                16, 0, 0);
            __builtin_amdgcn_global_load_lds(
                (const __attribute__((address_space(1))) unsigned*)(vg + i * 1024),
                (__attribute__((address_space(3))) unsigned*)(&Vt[buf][w * 4096 + i * 1024]),
                16, 0, 0);
        }
    };

    STAGE(0, 0);
    __syncthreads();

    for (int kt = 0; kt < 32; ++kt) {
        const int cur = kt & 1;
        const int kv0 = kt * 64;
        if (kt < 31) STAGE(kt + 1, cur ^ 1);

        // mexp A-frags (broadcast rows; shared by both halves)
        bf16x8 mf[2];
        #pragma unroll
        for (int blk = 0; blk < 2; ++blk)
            mf[blk] = *(const bf16x8*)(mep + kv0 + blk * 32 + g * 8);

        // ---- QK^T both halves; K frag loaded once per t2, used twice ----
        f32x4 s0[4], s1[4];
        #pragma unroll
        for (int t2 = 0; t2 < 4; ++t2) { s0[t2] = {0.f,0.f,0.f,0.f}; s1[t2] = {0.f,0.f,0.f,0.f}; }
        __builtin_amdgcn_s_setprio(1);
        #pragma unroll
        for (int t2 = 0; t2 < 4; ++t2) {
            const bf16x8 k0 = *(const bf16x8*)(&Kt[cur][(t2 * 16 + c) * 128
                                 + ((g * 16) ^ ((c & 7) << 4))]);
            const bf16x8 k1 = *(const bf16x8*)(&Kt[cur][(t2 * 16 + c) * 128
                                 + ((64 + g * 16) ^ ((c & 7) << 4))]);
            s0[t2] = __builtin_amdgcn_mfma_f32_16x16x32_bf16(k0, qf[0][0], s0[t2], 0, 0, 0);
            s0[t2] = __builtin_amdgcn_mfma_f32_16x16x32_bf16(k1, qf[0][1], s0[t2], 0, 0, 0);
            s1[t2] = __builtin_amdgcn_mfma_f32_16x16x32_bf16(k0, qf[1][0], s1[t2], 0, 0, 0);
            s1[t2] = __builtin_amdgcn_mfma_f32_16x16x32_bf16(k1, qf[1][1], s1[t2], 0, 0, 0);
        }
        __builtin_amdgcn_s_setprio(0);

        // ---- V^T fragments loaded once, used by both halves ----
        bf16x8 vfr[4][2];
        #pragma unroll
        for (int tt = 0; tt < 4; ++tt)
            #pragma unroll
            for (int blk = 0; blk < 2; ++blk)
                vfr[tt][blk] = *(const bf16x8*)(&Vt[cur][(tt * 16 + c) * 128
                                     + ((blk * 64 + g * 16) ^ ((c & 7) << 4))]);

        // ---- half 0: exp, P roundtrip, lsum + PV ----
        #pragma unroll
        for (int t2 = 0; t2 < 4; ++t2) {
            s0[t2][0] = EXP2(s0[t2][0]); s0[t2][1] = EXP2(s0[t2][1]);
            s0[t2][2] = EXP2(s0[t2][2]); s0[t2][3] = EXP2(s0[t2][3]);
        }
        #pragma unroll
        for (int t2 = 0; t2 < 4; ++t2) {
            uint2 pr;
            pr.x = cvtpk(s0[t2][0], s0[t2][1]);
            pr.y = cvtpk(s0[t2][2], s0[t2][3]);
            *(uint2*)&Pl[w][c][(8 * t2 + 2 * g) ^ ((c & 7) << 2)] = pr;
        }
        {
            bf16x8 pfr[2];
            #pragma unroll
            for (int blk = 0; blk < 2; ++blk)
                pfr[blk] = *(const bf16x8*)&Pl[w][c][(16 * blk + 4 * g) ^ ((c & 7) << 2)];
            __builtin_amdgcn_s_setprio(1);
            #pragma unroll
            for (int blk = 0; blk < 2; ++blk)
                ls0 = __builtin_amdgcn_mfma_f32_16x16x32_bf16(mf[blk], pfr[blk], ls0, 0, 0, 0);
            #pragma unroll
            for (int tt = 0; tt < 4; ++tt)
                #pragma unroll
                for (int blk = 0; blk < 2; ++blk)
                    o0[tt] = __builtin_amdgcn_mfma_f32_16x16x32_bf16(vfr[tt][blk], pfr[blk], o0[tt], 0, 0, 0);
            __builtin_amdgcn_s_setprio(0);
        }

        // ---- half 1: exp, P roundtrip (same buffer; same-wave order), PV ----
        #pragma unroll
        for (int t2 = 0; t2 < 4; ++t2) {
            s1[t2][0] = EXP2(s1[t2][0]); s1[t2][1] = EXP2(s1[t2][1]);
            s1[t2][2] = EXP2(s1[t2][2]); s1[t2][3] = EXP2(s1[t2][3]);
        }
        #pragma unroll
        for (int t2 = 0; t2 < 4; ++t2) {
            uint2 pr;
            pr.x = cvtpk(s1[t2][0], s1[t2][1]);
            pr.y = cvtpk(s1[t2][2], s1[t2][3]);
            *(uint2*)&Pl[w][c][(8 * t2 + 2 * g) ^ ((c & 7) << 2)] = pr;
        }
        {
            bf16x8 pfr[2];
            #pragma unroll
            for (int blk = 0; blk < 2; ++blk)
                pfr[blk] = *(const bf16x8*)&Pl[w][c][(16 * blk + 4 * g) ^ ((c & 7) << 2)];
            __builtin_amdgcn_s_setprio(1);
            #pragma unroll
            for (int blk = 0; blk < 2; ++blk)
                ls1 = __builtin_amdgcn_mfma_f32_16x16x32_bf16(mf[blk], pfr[blk], ls1, 0, 0, 0);
            #pragma unroll
            for (int tt = 0; tt < 4; ++tt)
                #pragma unroll
                for (int blk = 0; blk < 2; ++blk)
                    o1[tt] = __builtin_amdgcn_mfma_f32_16x16x32_bf16(vfr[tt][blk], pfr[blk], o1[tt], 0, 0, 0);
            __builtin_amdgcn_s_setprio(0);
        }

        __syncthreads();   // buf reuse + vmcnt drain for next tile (2 waves)
    }

    // ---- epilogue: both halves; denominator lane-uniform ----
    const float li0 = 1.f / ls0[0];
    const float li1 = 1.f / ls1[0];
    #pragma unroll
    for (int tt = 0; tt < 4; ++tt) {
        const size_t r0 = ((size_t)(b * SEQ + q0 + c) << 10) + h * 64 + 16 * tt + 4 * g;
        out[r0 + 0] = o0[tt][0] * li0;
        out[r0 + 1] = o0[tt][1] * li0;
        out[r0 + 2] = o0[tt][2] * li0;
        out[r0 + 3] = o0[tt][3] * li0;
        const size_t r1 = ((size_t)(b * SEQ + q0 + 16 + c) << 10) + h * 64 + 16 * tt + 4 * g;
        out[r1 + 0] = o1[tt][0] * li1;
        out[r1 + 1] = o1[tt][1] * li1;
        out[r1 + 2] = o1[tt][2] * li1;
        out[r1 + 3] = o1[tt][3] * li1;
    }
}

extern "C" void kernel_launch(void* const* d_in, const int* in_sizes, int n_in,
                              void* d_out, int out_size, void* d_ws, size_t ws_size,
                              hipStream_t stream) {
    const float* hid  = (const float*)d_in[0];
    const float* mask = (const float*)d_in[1];
    const float* Wq   = (const float*)d_in[2];
    const float* bq   = (const float*)d_in[3];
    const float* Wk   = (const float*)d_in[4];
    const float* bk   = (const float*)d_in[5];
    const float* Wv   = (const float*)d_in[6];
    const float* bv   = (const float*)d_in[7];
    float* out = (float*)d_out;

    char* ws = (char*)d_ws;
    unsigned short* qbf = (unsigned short*)(ws);                    // 8 MB
    char*           kbf = ws + 8388608;                             // 8 MB (tiled+swz)
    char*           vbf = ws + 16777216;                            // 8 MB (V^T tiled+swz, mexp-scaled)
    unsigned short* hbf = (unsigned short*)(ws + 25165824);         // 8 MB
    unsigned short* wqb = (unsigned short*)(ws + 33554432);         // 2 MB
    unsigned short* wkb = (unsigned short*)(ws + 35651584);         // 2 MB
    unsigned short* wvb = (unsigned short*)(ws + 37748736);         // 2 MB
    unsigned short* mxb = (unsigned short*)(ws + 39845888);         // 8 KB mexp table

    cvt_all<<<3586, 256, 0, stream>>>(hid, hbf, Wq, wqb, Wk, wkb, Wv, wvb,
                                      mask, mxb);
    qkv_gemm<<<dim3(24, 32), 256, 0, stream>>>(hbf, wqb, wkb, wvb,
                                               bq, bk, bv, mxb, qbf, kbf, vbf);
    attn_mfma<<<dim3(32, NHD, BSZ), 128, 0, stream>>>(qbf, kbf, vbf, mxb, out);
}

// Round 15
// 115.595 us; speedup vs baseline: 1.0670x; 1.0428x over previous
//
#include <hip/hip_runtime.h>
#include <hip/hip_bf16.h>
#include <math.h>

#define HSZ 1024
#define NHD 16
#define SEQ 2048
#define BSZ 2
#define MTOT (BSZ*SEQ)   // 4096

typedef __attribute__((ext_vector_type(4)))  float  f32x4;
typedef __attribute__((ext_vector_type(8)))  __bf16 bf16x8;

#define LOG2E 1.4426950408889634f

#if __has_builtin(__builtin_amdgcn_exp2f)
#define EXP2(x) __builtin_amdgcn_exp2f(x)
#else
#define EXP2(x) exp2f(x)
#endif

__device__ __forceinline__ unsigned short f2bf(float x) {
    union { float f; unsigned u; } v; v.f = x;
    unsigned r = v.u + 0x7FFFu + ((v.u >> 16) & 1u);
    return (unsigned short)(r >> 16);
}
__device__ __forceinline__ float bf2f(unsigned short u) {
    union { unsigned u; float f; } v; v.u = ((unsigned)u) << 16; return v.f;
}
__device__ __forceinline__ unsigned cvtpk(float lo, float hi) {
    unsigned r;
    asm("v_cvt_pk_bf16_f32 %0, %1, %2" : "=v"(r) : "v"(lo), "v"(hi));
    return r;
}

// ---------------------------------------------------------------------------
// fp32 -> bf16 bulk convert: hidden + Wq/Wk/Wv, plus mexp table
// ---------------------------------------------------------------------------
__global__ __launch_bounds__(256) void cvt_all(
    const float* __restrict__ h,  unsigned short* __restrict__ hd,
    const float* __restrict__ w0, unsigned short* __restrict__ w0d,
    const float* __restrict__ w1, unsigned short* __restrict__ w1d,
    const float* __restrict__ w2, unsigned short* __restrict__ w2d,
    const float* __restrict__ mask, unsigned short* __restrict__ mexpb)
{
    const int bid = blockIdx.x;
    if (bid >= 3584) {   // mexp path
        const int o = ((bid - 3584) * 256 + threadIdx.x) * 8;
        float4 a = *(const float4*)(mask + o);
        float4 b = *(const float4*)(mask + o + 4);
        uint4 v;
        v.x = f2bf(EXP2(a.x * LOG2E)) | ((unsigned)f2bf(EXP2(a.y * LOG2E)) << 16);
        v.y = f2bf(EXP2(a.z * LOG2E)) | ((unsigned)f2bf(EXP2(a.w * LOG2E)) << 16);
        v.z = f2bf(EXP2(b.x * LOG2E)) | ((unsigned)f2bf(EXP2(b.y * LOG2E)) << 16);
        v.w = f2bf(EXP2(b.z * LOG2E)) | ((unsigned)f2bf(EXP2(b.w * LOG2E)) << 16);
        *(uint4*)(mexpb + o) = v;
        return;
    }
    const float* s; unsigned short* d; int i;
    if (bid < 2048)      { s = h;  d = hd;  i = bid; }
    else if (bid < 2560) { s = w0; d = w0d; i = bid - 2048; }
    else if (bid < 3072) { s = w1; d = w1d; i = bid - 2560; }
    else                 { s = w2; d = w2d; i = bid - 3072; }
    const int o = (i * 256 + threadIdx.x) * 8;
    float4 a = *(const float4*)(s + o);
    float4 b = *(const float4*)(s + o + 4);
    uint4 v;
    v.x = f2bf(a.x) | ((unsigned)f2bf(a.y) << 16);
    v.y = f2bf(a.z) | ((unsigned)f2bf(a.w) << 16);
    v.z = f2bf(b.x) | ((unsigned)f2bf(b.y) << 16);
    v.w = f2bf(b.z) | ((unsigned)f2bf(b.w) << 16);
    *(uint4*)(d + o) = v;
}

// ---------------------------------------------------------------------------
// Fused QKV GEMM, bf16 MFMA — BK=32 (verified fast). q scaled 0.125*log2e.
// V-blocks pre-load mexp factors before the K-loop (register-only epilogue).
// ---------------------------------------------------------------------------
__global__ __launch_bounds__(256) void qkv_gemm(
    const unsigned short* __restrict__ hb,
    const unsigned short* __restrict__ wq,
    const unsigned short* __restrict__ wk,
    const unsigned short* __restrict__ wv,
    const float* __restrict__ bq, const float* __restrict__ bk,
    const float* __restrict__ bv, const unsigned short* __restrict__ mexpb,
    unsigned short* __restrict__ qo, char* __restrict__ ko,
    char* __restrict__ vo)
{
    __shared__ __align__(16) unsigned short As[128 * 32];   // 8 KB
    __shared__ __align__(16) unsigned short Bs[128 * 32];   // 8 KB

    const int t = threadIdx.x;
    const int w = t >> 6, l = t & 63, g = l >> 4, c = l & 15;
    const int bn = blockIdx.x, bm = blockIdx.y;
    const int which = bn >> 3;
    const int n0 = (bn & 7) << 7;
    const int m0 = bm << 7;
    const unsigned short* W = (which == 0) ? wq : (which == 1) ? wk : wv;
    const float* bb = (which == 0) ? bq : (which == 1) ? bk : bv;
    const float scale = (which == 0) ? 0.125f * LOG2E : 1.0f;
    const int wr = w >> 1, wc = w & 1;

    float mexpf[16];
    if (which == 2) {
        #pragma unroll
        for (int mi = 0; mi < 4; ++mi) {
            const int mrow = m0 + wr * 64 + mi * 16 + g * 4;
            const int bi = mrow >> 11, si = mrow & 2047;
            const unsigned short* mp = mexpb + bi * SEQ + si;
            uint2 mv = *(const uint2*)mp;
            mexpf[mi * 4 + 0] = bf2f((unsigned short)(mv.x & 0xFFFF));
            mexpf[mi * 4 + 1] = bf2f((unsigned short)(mv.x >> 16));
            mexpf[mi * 4 + 2] = bf2f((unsigned short)(mv.y & 0xFFFF));
            mexpf[mi * 4 + 3] = bf2f((unsigned short)(mv.y >> 16));
        }
    }

    f32x4 acc[4][4];
    #pragma unroll
    for (int mi = 0; mi < 4; ++mi)
        #pragma unroll
        for (int ni = 0; ni < 4; ++ni) acc[mi][ni] = {0.f, 0.f, 0.f, 0.f};

    for (int k0 = 0; k0 < HSZ; k0 += 32) {
        #pragma unroll
        for (int i2 = 0; i2 < 2; ++i2) {
            const int chunk = 2 * w + i2;
            const int row = (chunk << 4) + (l >> 2);
            const int sg = (l & 3) ^ ((row >> 1) & 3);
            const char* ga = (const char*)hb +
                (((size_t)(m0 + row) << 10) + k0) * 2 + sg * 16;
            const char* gb = (const char*)W +
                (((size_t)(n0 + row) << 10) + k0) * 2 + sg * 16;
            __builtin_amdgcn_global_load_lds(
                (const __attribute__((address_space(1))) unsigned*)ga,
                (__attribute__((address_space(3))) unsigned*)((char*)As + chunk * 1024),
                16, 0, 0);
            __builtin_amdgcn_global_load_lds(
                (const __attribute__((address_space(1))) unsigned*)gb,
                (__attribute__((address_space(3))) unsigned*)((char*)Bs + chunk * 1024),
                16, 0, 0);
        }
        __syncthreads();

        bf16x8 af[4], bfr[4];
        #pragma unroll
        for (int mi = 0; mi < 4; ++mi) {
            const int row = wr * 64 + mi * 16 + c;
            const int gg = g ^ ((row >> 1) & 3);
            af[mi] = *(const bf16x8*)((const char*)As + row * 64 + gg * 16);
        }
        #pragma unroll
        for (int ni = 0; ni < 4; ++ni) {
            const int row = wc * 64 + ni * 16 + c;
            const int gg = g ^ ((row >> 1) & 3);
            bfr[ni] = *(const bf16x8*)((const char*)Bs + row * 64 + gg * 16);
        }
        #pragma unroll
        for (int mi = 0; mi < 4; ++mi)
            #pragma unroll
            for (int ni = 0; ni < 4; ++ni)
                acc[mi][ni] = __builtin_amdgcn_mfma_f32_16x16x32_bf16(
                    af[mi], bfr[ni], acc[mi][ni], 0, 0, 0);
        __syncthreads();
    }

    #pragma unroll
    for (int ni = 0; ni < 4; ++ni) {
        const int ncol = n0 + wc * 64 + ni * 16 + c;
        const int hh = ncol >> 6, d = ncol & 63;
        const float bsc = bb[ncol] * scale;
        #pragma unroll
        for (int mi = 0; mi < 4; ++mi) {
            #pragma unroll
            for (int j = 0; j < 4; ++j) {
                const int mrow = m0 + wr * 64 + mi * 16 + g * 4 + j;
                const int bi = mrow >> 11, si = mrow & 2047;
                float vf = acc[mi][ni][j] * scale + bsc;
                if (which == 2) vf *= mexpf[mi * 4 + j];
                const unsigned short val = f2bf(vf);
                const size_t bhoff = (size_t)(bi * NHD + hh);
                if (which == 0) {
                    qo[((bhoff * SEQ + si) << 6) + d] = val;
                } else if (which == 1) {
                    char* p = ko + (bhoff << 18) + ((size_t)(si >> 6) << 13)
                            + ((si & 63) << 7) + (((d << 1)) ^ ((si & 7) << 4));
                    *(unsigned short*)p = val;
                } else {
                    char* p = vo + (bhoff << 18) + ((size_t)(si >> 6) << 13)
                            + (d << 7) + (((si & 63) << 1) ^ ((d & 7) << 4));
                    *(unsigned short*)p = val;
                }
            }
        }
    }
}

// ---------------------------------------------------------------------------
// Flash attention: round-12 compute body (4 waves, 32 q-rows/wave) with T4
// sync: TRIPLE-buffered K/V + counted s_waitcnt vmcnt(4) + raw s_barrier.
// Prefetch for kt+1 stays IN FLIGHT across the barrier (never drained);
// compute(kt) only waits for loads issued a full iteration earlier.
// Max-free softmax; mask pre-folded into V; denominator via MFMA.
// Grid 16 x NHD x BSZ = 512 blocks of 256 threads; LDS 57344 B (2/CU).
// ---------------------------------------------------------------------------
__global__ __launch_bounds__(256) void attn_mfma(
    const unsigned short* __restrict__ qb, const char* __restrict__ kb,
    const char* __restrict__ vb, const unsigned short* __restrict__ mexpb,
    float* __restrict__ out)
{
    __shared__ __align__(16) char Kt[3][8192];
    __shared__ __align__(16) char Vt[3][8192];
    __shared__ __align__(16) unsigned Pl[4][16][32];   // total 57344 B

    const int t = threadIdx.x;
    const int w = t >> 6, l = t & 63, g = l >> 4, c = l & 15;
    const int qt = blockIdx.x, h = blockIdx.y, b = blockIdx.z;
    const int bh = b * NHD + h;
    const int q0 = qt * 128 + w * 32;

    const unsigned short* qp = qb + ((size_t)bh * SEQ + q0) * 64;
    const char* kbase = kb + ((size_t)bh << 18);
    const char* vbase = vb + ((size_t)bh << 18);
    const unsigned short* mep = mexpb + b * SEQ;

    bf16x8 qf[2][2];
    #pragma unroll
    for (int qh = 0; qh < 2; ++qh)
        #pragma unroll
        for (int p = 0; p < 2; ++p)
            qf[qh][p] = *(const bf16x8*)(qp + (qh * 16 + c) * 64 + p * 32 + g * 8);

    f32x4 o0[4], o1[4];
    #pragma unroll
    for (int tt = 0; tt < 4; ++tt) { o0[tt] = {0.f,0.f,0.f,0.f}; o1[tt] = {0.f,0.f,0.f,0.f}; }
    f32x4 ls0 = {0.f,0.f,0.f,0.f}, ls1 = {0.f,0.f,0.f,0.f};

    // wave w stages bytes [w*2048, w*2048+2048) of each 8KB tile: 4 loads total
    auto STAGE = [&](int tile, int buf) {
        const char* kg = kbase + tile * 8192 + w * 2048 + l * 16;
        const char* vg = vbase + tile * 8192 + w * 2048 + l * 16;
        #pragma unroll
        for (int i = 0; i < 2; ++i) {
            __builtin_amdgcn_global_load_lds(
                (const __attribute__((address_space(1))) unsigned*)(kg + i * 1024),
                (__attribute__((address_space(3))) unsigned*)(&Kt[buf][w * 2048 + i * 1024]),
                16, 0, 0);
            __builtin_amdgcn_global_load_lds(
                (const __attribute__((address_space(1))) unsigned*)(vg + i * 1024),
                (__attribute__((address_space(3))) unsigned*)(&Vt[buf][w * 2048 + i * 1024]),
                16, 0, 0);
        }
    };

    STAGE(0, 0);
    STAGE(1, 1);

    int cur = 0;
    for (int kt = 0; kt < 32; ++kt) {
        const int kv0 = kt * 64;

        // T4: wait only for STAGE(kt) (issued one iteration ago); the 4
        // newest loads (STAGE(kt+1)) stay in flight across the barrier.
        if (kt >= 30) { asm volatile("s_waitcnt vmcnt(0)" ::: "memory"); }
        else          { asm volatile("s_waitcnt vmcnt(4)" ::: "memory"); }
        __builtin_amdgcn_s_barrier();
        __builtin_amdgcn_sched_barrier(0);

        // prefetch kt+2 into the slot last read at kt-1 (sealed by barrier)
        if (kt < 30) {
            int slot = cur + 2; if (slot >= 3) slot -= 3;
            STAGE(kt + 2, slot);
        }

        // mexp A-frags (broadcast rows; shared by both halves)
        bf16x8 mf[2];
        #pragma unroll
        for (int blk = 0; blk < 2; ++blk)
            mf[blk] = *(const bf16x8*)(mep + kv0 + blk * 32 + g * 8);

        // ---- QK^T both halves; K frag loaded once per t2, used twice ----
        f32x4 s0[4], s1[4];
        #pragma unroll
        for (int t2 = 0; t2 < 4; ++t2) { s0[t2] = {0.f,0.f,0.f,0.f}; s1[t2] = {0.f,0.f,0.f,0.f}; }
        __builtin_amdgcn_s_setprio(1);
        #pragma unroll
        for (int t2 = 0; t2 < 4; ++t2) {
            const bf16x8 k0 = *(const bf16x8*)(&Kt[cur][(t2 * 16 + c) * 128
                                 + ((g * 16) ^ ((c & 7) << 4))]);
            const bf16x8 k1 = *(const bf16x8*)(&Kt[cur][(t2 * 16 + c) * 128
                                 + ((64 + g * 16) ^ ((c & 7) << 4))]);
            s0[t2] = __builtin_amdgcn_mfma_f32_16x16x32_bf16(k0, qf[0][0], s0[t2], 0, 0, 0);
            s0[t2] = __builtin_amdgcn_mfma_f32_16x16x32_bf16(k1, qf[0][1], s0[t2], 0, 0, 0);
            s1[t2] = __builtin_amdgcn_mfma_f32_16x16x32_bf16(k0, qf[1][0], s1[t2], 0, 0, 0);
            s1[t2] = __builtin_amdgcn_mfma_f32_16x16x32_bf16(k1, qf[1][1], s1[t2], 0, 0, 0);
        }
        __builtin_amdgcn_s_setprio(0);

        // ---- V^T fragments loaded once, used by both halves ----
        bf16x8 vfr[4][2];
        #pragma unroll
        for (int tt = 0; tt < 4; ++tt)
            #pragma unroll
            for (int blk = 0; blk < 2; ++blk)
                vfr[tt][blk] = *(const bf16x8*)(&Vt[cur][(tt * 16 + c) * 128
                                     + ((blk * 64 + g * 16) ^ ((c & 7) << 4))]);

        // ---- half 0 ----
        #pragma unroll
        for (int t2 = 0; t2 < 4; ++t2) {
            s0[t2][0] = EXP2(s0[t2][0]); s0[t2][1] = EXP2(s0[t2][1]);
            s0[t2][2] = EXP2(s0[t2][2]); s0[t2][3] = EXP2(s0[t2][3]);
        }
        #pragma unroll
        for (int t2 = 0; t2 < 4; ++t2) {
            uint2 pr;
            pr.x = cvtpk(s0[t2][0], s0[t2][1]);
            pr.y = cvtpk(s0[t2][2], s0[t2][3]);
            *(uint2*)&Pl[w][c][(8 * t2 + 2 * g) ^ ((c & 7) << 2)] = pr;
        }
        {
            bf16x8 pfr[2];
            #pragma unroll
            for (int blk = 0; blk < 2; ++blk)
                pfr[blk] = *(const bf16x8*)&Pl[w][c][(16 * blk + 4 * g) ^ ((c & 7) << 2)];
            __builtin_amdgcn_s_setprio(1);
            #pragma unroll
            for (int blk = 0; blk < 2; ++blk)
                ls0 = __builtin_amdgcn_mfma_f32_16x16x32_bf16(mf[blk], pfr[blk], ls0, 0, 0, 0);
            #pragma unroll
            for (int tt = 0; tt < 4; ++tt)
                #pragma unroll
                for (int blk = 0; blk < 2; ++blk)
                    o0[tt] = __builtin_amdgcn_mfma_f32_16x16x32_bf16(vfr[tt][blk], pfr[blk], o0[tt], 0, 0, 0);
            __builtin_amdgcn_s_setprio(0);
        }

        // ---- half 1 (same Pl buffer; same-wave DS ordering) ----
        #pragma unroll
        for (int t2 = 0; t2 < 4; ++t2) {
            s1[t2][0] = EXP2(s1[t2][0]); s1[t2][1] = EXP2(s1[t2][1]);
            s1[t2][2] = EXP2(s1[t2][2]); s1[t2][3] = EXP2(s1[t2][3]);
        }
        #pragma unroll
        for (int t2 = 0; t2 < 4; ++t2) {
            uint2 pr;
            pr.x = cvtpk(s1[t2][0], s1[t2][1]);
            pr.y = cvtpk(s1[t2][2], s1[t2][3]);
            *(uint2*)&Pl[w][c][(8 * t2 + 2 * g) ^ ((c & 7) << 2)] = pr;
        }
        {
            bf16x8 pfr[2];
            #pragma unroll
            for (int blk = 0; blk < 2; ++blk)
                pfr[blk] = *(const bf16x8*)&Pl[w][c][(16 * blk + 4 * g) ^ ((c & 7) << 2)];
            __builtin_amdgcn_s_setprio(1);
            #pragma unroll
            for (int blk = 0; blk < 2; ++blk)
                ls1 = __builtin_amdgcn_mfma_f32_16x16x32_bf16(mf[blk], pfr[blk], ls1, 0, 0, 0);
            #pragma unroll
            for (int tt = 0; tt < 4; ++tt)
                #pragma unroll
                for (int blk = 0; blk < 2; ++blk)
                    o1[tt] = __builtin_amdgcn_mfma_f32_16x16x32_bf16(vfr[tt][blk], pfr[blk], o1[tt], 0, 0, 0);
            __builtin_amdgcn_s_setprio(0);
        }

        ++cur; if (cur == 3) cur = 0;
    }

    // ---- epilogue: both halves; denominator lane-uniform ----
    const float li0 = 1.f / ls0[0];
    const float li1 = 1.f / ls1[0];
    #pragma unroll
    for (int tt = 0; tt < 4; ++tt) {
        const size_t r0 = ((size_t)(b * SEQ + q0 + c) << 10) + h * 64 + 16 * tt + 4 * g;
        out[r0 + 0] = o0[tt][0] * li0;
        out[r0 + 1] = o0[tt][1] * li0;
        out[r0 + 2] = o0[tt][2] * li0;
        out[r0 + 3] = o0[tt][3] * li0;
        const size_t r1 = ((size_t)(b * SEQ + q0 + 16 + c) << 10) + h * 64 + 16 * tt + 4 * g;
        out[r1 + 0] = o1[tt][0] * li1;
        out[r1 + 1] = o1[tt][1] * li1;
        out[r1 + 2] = o1[tt][2] * li1;
        out[r1 + 3] = o1[tt][3] * li1;
    }
}

extern "C" void kernel_launch(void* const* d_in, const int* in_sizes, int n_in,
                              void* d_out, int out_size, void* d_ws, size_t ws_size,
                              hipStream_t stream) {
    const float* hid  = (const float*)d_in[0];
    const float* mask = (const float*)d_in[1];
    const float* Wq   = (const float*)d_in[2];
    const float* bq   = (const float*)d_in[3];
    const float* Wk   = (const float*)d_in[4];
    const float* bk   = (const float*)d_in[5];
    const float* Wv   = (const float*)d_in[6];
    const float* bv   = (const float*)d_in[7];
    float* out = (float*)d_out;

    char* ws = (char*)d_ws;
    unsigned short* qbf = (unsigned short*)(ws);                    // 8 MB
    char*           kbf = ws + 8388608;                             // 8 MB (tiled+swz)
    char*           vbf = ws + 16777216;                            // 8 MB (V^T tiled+swz, mexp-scaled)
    unsigned short* hbf = (unsigned short*)(ws + 25165824);         // 8 MB
    unsigned short* wqb = (unsigned short*)(ws + 33554432);         // 2 MB
    unsigned short* wkb = (unsigned short*)(ws + 35651584);         // 2 MB
    unsigned short* wvb = (unsigned short*)(ws + 37748736);         // 2 MB
    unsigned short* mxb = (unsigned short*)(ws + 39845888);         // 8 KB mexp table

    cvt_all<<<3586, 256, 0, stream>>>(hid, hbf, Wq, wqb, Wk, wkb, Wv, wvb,
                                      mask, mxb);
    qkv_gemm<<<dim3(24, 32), 256, 0, stream>>>(hbf, wqb, wkb, wvb,
                                               bq, bk, bv, mxb, qbf, kbf, vbf);
    attn_mfma<<<dim3(16, NHD, BSZ), 256, 0, stream>>>(qbf, kbf, vbf, mxb, out);
}